// Round 1
// baseline (264.628 us; speedup 1.0000x reference)
//
#include <hip/hip_runtime.h>
#include <math.h>

#define NTOK    8192
#define DIM     4096
#define NEXP    64
#define TOPK_N  8
#define TAU     2.0e-4f
#define KSPLIT  8                        // waves per block = k-eighths
#define KSTEPS  ((DIM / KSPLIT) / 32)    // 16 k-steps of 32
#define TB      16                       // tokens per block (was 32)

#define WS_WHI_OFF  0
#define WS_WLO_OFF  524288

typedef __attribute__((ext_vector_type(8))) short short8;   // 8 bf16
typedef __attribute__((ext_vector_type(4))) float f32x4;

// fp32 -> bf16 hi (trunc) + bf16 lo (trunc of exact residual)
__device__ __forceinline__ void cvt8(float4 a0, float4 a1, short8& hv, short8& lv) {
    float f[8] = {a0.x, a0.y, a0.z, a0.w, a1.x, a1.y, a1.z, a1.w};
    union { short8 v; unsigned u[4]; } H, L;
    #pragma unroll
    for (int i = 0; i < 4; ++i) {
        unsigned b0 = __float_as_uint(f[2*i]);
        unsigned b1 = __float_as_uint(f[2*i+1]);
        float r0 = f[2*i]   - __uint_as_float(b0 & 0xffff0000u);
        float r1 = f[2*i+1] - __uint_as_float(b1 & 0xffff0000u);
        H.u[i] = (b0 >> 16) | (b1 & 0xffff0000u);
        L.u[i] = (__float_as_uint(r0) >> 16) | (__float_as_uint(r1) & 0xffff0000u);
    }
    hv = H.v; lv = L.v;
}

// ---------------- Pass 0: w fp32 -> bf16 hi/lo (8 floats/thread, 128 blocks) ----------------
__global__ __launch_bounds__(256, 4)
void cvt_w_kernel(const float* __restrict__ w, unsigned short* __restrict__ whi,
                  unsigned short* __restrict__ wlo) {
    const int g = blockIdx.x * 256 + threadIdx.x;
    const float* p = w + (size_t)g * 8;
    union { short8 v; uint4 q; } H, L;
    float4 a0 = *(const float4*)(p);
    float4 a1 = *(const float4*)(p + 4);
    cvt8(a0, a1, H.v, L.v);
    *(uint4*)(whi + (size_t)g * 8) = H.q;
    *(uint4*)(wlo + (size_t)g * 8) = L.q;
}

// ---------------- Pass 1: fused MFMA bf16x3 GEMM + softmax + top-8 + fp64 recheck ----------------
// block = 512 thr = 8 waves. Block covers 16 tokens x 64 experts; wave wv = k-eighth.
// Grid 512 blocks -> 2 blocks/CU, 16 waves/CU. Register double-buffer fits under 128 VGPR.
__global__ __launch_bounds__(512, 4)
void gemm_kernel(const float* __restrict__ x, const unsigned short* __restrict__ whi,
                 const unsigned short* __restrict__ wlo, const float* __restrict__ bias,
                 const float* __restrict__ wfp, float* __restrict__ out, int ntok) {
    __shared__ float  lds_part[KSPLIT][TB][65];   // 33.3 KB
    __shared__ float  lds_s[TB][68];              // 4.35 KB (68: 16B-aligned rows, conflict-free)
    __shared__ float  top9[TB][9];
    __shared__ double dsc[NEXP];
    __shared__ int    nflag;
    __shared__ int    ftok[TB];
    __shared__ float  fninth[TB];

    const int tid  = threadIdx.x;
    const int lane = tid & 63;
    const int wv   = tid >> 6;
    const int nl   = lane & 15;
    const int q    = lane >> 4;
    const int tok0 = blockIdx.x * TB;
    if (tid == 0) nflag = 0;

    const int kbase = wv * (DIM / KSPLIT);
    const float* xr = x + (size_t)(tok0 + nl) * DIM;
    size_t boff[4];
    #pragma unroll
    for (int nf = 0; nf < 4; ++nf) boff[nf] = (size_t)(nf * 16 + nl) * DIM;

    f32x4 acc[4];
    #pragma unroll
    for (int nf = 0; nf < 4; ++nf) acc[nf] = (f32x4){0.f, 0.f, 0.f, 0.f};

    float4 Ar[2][2];             // [buf][half]
    short8 Bh[2][4], Bl[2][4];   // [buf][nf]

    // prologue loads (buf 0)
    {
        const int k0 = kbase + q * 8;
        Ar[0][0] = *(const float4*)(xr + k0);
        Ar[0][1] = *(const float4*)(xr + k0 + 4);
        #pragma unroll
        for (int nf = 0; nf < 4; ++nf) {
            Bh[0][nf] = *(const short8*)(whi + boff[nf] + k0);
            Bl[0][nf] = *(const short8*)(wlo + boff[nf] + k0);
        }
    }

    #pragma unroll 2
    for (int ks = 0; ks < KSTEPS; ++ks) {
        const int buf = ks & 1, nxt = buf ^ 1;
        if (ks + 1 < KSTEPS) {   // prefetch next step
            const int k1 = kbase + (ks + 1) * 32 + q * 8;
            Ar[nxt][0] = *(const float4*)(xr + k1);
            Ar[nxt][1] = *(const float4*)(xr + k1 + 4);
            #pragma unroll
            for (int nf = 0; nf < 4; ++nf) {
                Bh[nxt][nf] = *(const short8*)(whi + boff[nf] + k1);
                Bl[nxt][nf] = *(const short8*)(wlo + boff[nf] + k1);
            }
        }
        short8 ahi, alo;
        cvt8(Ar[buf][0], Ar[buf][1], ahi, alo);
        #pragma unroll
        for (int nf = 0; nf < 4; ++nf) {
            acc[nf] = __builtin_amdgcn_mfma_f32_16x16x32_bf16(ahi, Bl[buf][nf], acc[nf], 0, 0, 0);
            acc[nf] = __builtin_amdgcn_mfma_f32_16x16x32_bf16(alo, Bh[buf][nf], acc[nf], 0, 0, 0);
            acc[nf] = __builtin_amdgcn_mfma_f32_16x16x32_bf16(ahi, Bh[buf][nf], acc[nf], 0, 0, 0);
        }
    }

    // partials -> LDS (C/D layout: col=lane&15 -> expert, row=q*4+r -> token-in-group)
    #pragma unroll
    for (int nf = 0; nf < 4; ++nf)
        #pragma unroll
        for (int r = 0; r < 4; ++r)
            lds_part[wv][q * 4 + r][nf * 16 + nl] = acc[nf][r];
    __syncthreads();

    // reduce 8 partials (fixed order), add bias: 1024 values / 512 threads
    #pragma unroll
    for (int i = 0; i < (TB * NEXP) / 512; ++i) {
        const int p  = tid + i * 512;
        const int tk = p >> 6, e = p & 63;
        float s = lds_part[0][tk][e];
        #pragma unroll
        for (int k = 1; k < KSPLIT; ++k) s += lds_part[k][tk][e];
        lds_s[tk][e] = s + bias[e];
    }
    __syncthreads();

    // softmax + parallel-rank top-k: wave wv -> tokens wv*2..+2, lane = expert
    float* __restrict__ out_idx = out + (size_t)ntok * NEXP;
    #pragma unroll
    for (int t = 0; t < 2; ++t) {
        const int tokl = wv * 2 + t;
        const int tok  = tok0 + tokl;
        const float s  = lds_s[tokl][lane];

        // max + sum via butterfly (numerics identical to previous kernel)
        float m = s;
        #pragma unroll
        for (int off = 32; off > 0; off >>= 1)
            m = fmaxf(m, __shfl_xor(m, off, 64));
        const float ex = expf(s - m);
        float sum = ex;
        #pragma unroll
        for (int off = 32; off > 0; off >>= 1)
            sum += __shfl_xor(sum, off, 64);
        out[(size_t)tok * NEXP + lane] = ex / sum;

        // rank = #{j : v_j > s || (v_j == s && j < lane)} — replaces 9 serial argmax rounds.
        // Broadcast float4 row reads from LDS (all lanes same addr -> conflict-free).
        int rank = 0;
        #pragma unroll
        for (int i = 0; i < 16; ++i) {
            const float4 v4 = *(const float4*)(&lds_s[tokl][i * 4]);
            rank += (int)((v4.x > s) || (v4.x == s && (i * 4 + 0) < lane));
            rank += (int)((v4.y > s) || (v4.y == s && (i * 4 + 1) < lane));
            rank += (int)((v4.z > s) || (v4.z == s && (i * 4 + 2) < lane));
            rank += (int)((v4.w > s) || (v4.w == s && (i * 4 + 3) < lane));
        }
        if (rank < TOPK_N + 1) top9[tokl][rank] = s;
        if (rank < TOPK_N)
            out_idx[(size_t)tok * TOPK_N + rank] = (float)lane;
    }
    __syncthreads();

    // tie-screen: 16 threads, one per token, scan the 8 gaps of top-9
    if (tid < TB) {
        float ming = 1e30f;
        #pragma unroll
        for (int r = 0; r < TOPK_N; ++r)
            ming = fminf(ming, top9[tid][r] - top9[tid][r + 1]);
        if (ming < TAU) {
            const int sl = atomicAdd(&nflag, 1);
            ftok[sl] = tid;
            fninth[sl] = top9[tid][TOPK_N];   // 9th-best fp32 score
        }
    }
    __syncthreads();

    // inline fp64 recheck of flagged tokens (block-local, rare)
    const int nfl = nflag;
    for (int i = 0; i < nfl; ++i) {
        const int tokl = ftok[i];
        const int tok  = tok0 + tokl;
        const float thr = fninth[i] - TAU;
        const unsigned long long cmask = __ballot(lds_s[tokl][lane] >= thr);
        if (wv == 0) dsc[lane] = -1.0e300;
        __syncthreads();
        // wave wv handles candidate ranks wv, wv+8, ...
        {
            int rank = 0;
            unsigned long long mm = cmask;
            while (mm) {
                const int e = __builtin_ctzll(mm);
                mm &= mm - 1;
                if ((rank & 7) == wv) {
                    const float* wr  = wfp + (size_t)e * DIM;
                    const float* xrr = x + (size_t)tok * DIM;
                    double a = 0.0;
                    #pragma unroll 4
                    for (int kk = 0; kk < 16; ++kk) {
                        const int k = kk * 256 + lane * 4;
                        const float4 wv4 = *(const float4*)(wr + k);
                        const float4 xv  = *(const float4*)(xrr + k);
                        a = fma((double)xv.x, (double)wv4.x, a);
                        a = fma((double)xv.y, (double)wv4.y, a);
                        a = fma((double)xv.z, (double)wv4.z, a);
                        a = fma((double)xv.w, (double)wv4.w, a);
                    }
                    #pragma unroll
                    for (int off = 32; off > 0; off >>= 1)
                        a += __shfl_xor(a, off, 64);
                    if (lane == 0) dsc[e] = a + (double)bias[e];
                }
                ++rank;
            }
        }
        __syncthreads();
        if (wv == 0) {
            double cv = dsc[lane];
            for (int r = 0; r < TOPK_N; ++r) {
                double bv = cv;
                int    bi = lane;
                #pragma unroll
                for (int off = 32; off > 0; off >>= 1) {
                    const double ov = __shfl_xor(bv, off, 64);
                    const int    oi = __shfl_xor(bi, off, 64);
                    if (ov > bv || (ov == bv && oi < bi)) { bv = ov; bi = oi; }
                }
                if (lane == r)
                    out_idx[(size_t)tok * TOPK_N + r] = (float)bi;
                if (lane == bi) cv = -1.0e301;
            }
        }
        __syncthreads();
    }
}

extern "C" void kernel_launch(void* const* d_in, const int* in_sizes, int n_in,
                              void* d_out, int out_size, void* d_ws, size_t ws_size,
                              hipStream_t stream) {
    const float* x  = (const float*)d_in[0];
    const float* w  = (const float*)d_in[1];
    const float* bs = (const float*)d_in[2];
    float* out = (float*)d_out;

    unsigned short* whi = (unsigned short*)((char*)d_ws + WS_WHI_OFF);
    unsigned short* wlo = (unsigned short*)((char*)d_ws + WS_WLO_OFF);

    const int ntok = in_sizes[0] / DIM;          // 8192

    hipLaunchKernelGGL(cvt_w_kernel, dim3((NEXP * DIM) / 8 / 256), dim3(256), 0, stream,
                       w, whi, wlo);
    hipLaunchKernelGGL(gemm_kernel, dim3(ntok / TB), dim3(512), 0, stream,
                       x, whi, wlo, bs, w, out, ntok);
}

// Round 2
// 243.106 us; speedup vs baseline: 1.0885x; 1.0885x over previous
//
#include <hip/hip_runtime.h>
#include <math.h>

#define NTOK    8192
#define DIM     4096
#define NEXP    64
#define TOPK_N  8
#define TAU     2.0e-4f
#define KSPLIT  8                        // waves per block = k-eighths
#define KSTEPS  ((DIM / KSPLIT) / 32)    // 16 k-steps of 32
#define TB      32                       // tokens per block

#define WS_WHI_OFF  0
#define WS_WLO_OFF  524288

typedef __attribute__((ext_vector_type(8))) short short8;   // 8 bf16
typedef __attribute__((ext_vector_type(4))) float f32x4;

// fp32 -> bf16 hi (trunc) + bf16 lo (trunc of exact residual)
__device__ __forceinline__ void cvt8(float4 a0, float4 a1, short8& hv, short8& lv) {
    float f[8] = {a0.x, a0.y, a0.z, a0.w, a1.x, a1.y, a1.z, a1.w};
    union { short8 v; unsigned u[4]; } H, L;
    #pragma unroll
    for (int i = 0; i < 4; ++i) {
        unsigned b0 = __float_as_uint(f[2*i]);
        unsigned b1 = __float_as_uint(f[2*i+1]);
        float r0 = f[2*i]   - __uint_as_float(b0 & 0xffff0000u);
        float r1 = f[2*i+1] - __uint_as_float(b1 & 0xffff0000u);
        H.u[i] = (b0 >> 16) | (b1 & 0xffff0000u);
        L.u[i] = (__float_as_uint(r0) >> 16) | (__float_as_uint(r1) & 0xffff0000u);
    }
    hv = H.v; lv = L.v;
}

// ---------------- Pass 0: w fp32 -> bf16 hi/lo ----------------
__global__ __launch_bounds__(256, 4)
void cvt_w_kernel(const float* __restrict__ w, unsigned short* __restrict__ whi,
                  unsigned short* __restrict__ wlo) {
    const int g = blockIdx.x * 256 + threadIdx.x;
    const float* p = w + (size_t)g * 8;
    union { short8 v; uint4 q; } H, L;
    float4 a0 = *(const float4*)(p);
    float4 a1 = *(const float4*)(p + 4);
    cvt8(a0, a1, H.v, L.v);
    *(uint4*)(whi + (size_t)g * 8) = H.q;
    *(uint4*)(wlo + (size_t)g * 8) = L.q;
}

// ---------------- Pass 1: fused MFMA bf16x3 GEMM + softmax + top-8 + fp64 recheck ----------------
// block = 512 thr = 8 waves, TB=32 tokens x 64 experts, wave wv = k-eighth.
// Register double-buffer K-loop with sched_barrier(0) walls: prefetch issue for step
// s+1 is pinned BEFORE compute of step s, so the compiler's auto-waitcnt becomes a
// counted vmcnt(12) (12 loads in flight across each compute phase) instead of a full
// per-step drain. No barriers in the K-loop.
__global__ __launch_bounds__(512, 2)
void gemm_kernel(const float* __restrict__ x, const unsigned short* __restrict__ whi,
                 const unsigned short* __restrict__ wlo, const float* __restrict__ bias,
                 const float* __restrict__ wfp, float* __restrict__ out, int ntok) {
    __shared__ float  lds_part[KSPLIT][TB][65];   // 66.6 KB
    __shared__ float  lds_s[TB][68];              // 8.7 KB (16B-aligned rows)
    __shared__ float  top9[TB][9];
    __shared__ double dsc[NEXP];
    __shared__ int    nflag;
    __shared__ int    ftok[TB];
    __shared__ float  fninth[TB];

    const int tid  = threadIdx.x;
    const int lane = tid & 63;
    const int wv   = tid >> 6;
    const int nl   = lane & 15;
    const int q    = lane >> 4;
    const int tok0 = blockIdx.x * TB;
    if (tid == 0) nflag = 0;

    const int kbase = wv * (DIM / KSPLIT);
    const float* xr[2] = { x + (size_t)(tok0 + nl) * DIM,
                           x + (size_t)(tok0 + 16 + nl) * DIM };
    size_t boff[4];
    #pragma unroll
    for (int nf = 0; nf < 4; ++nf) boff[nf] = (size_t)(nf * 16 + nl) * DIM;

    f32x4 acc[2][4];
    #pragma unroll
    for (int mg = 0; mg < 2; ++mg)
        #pragma unroll
        for (int nf = 0; nf < 4; ++nf) acc[mg][nf] = (f32x4){0.f, 0.f, 0.f, 0.f};

    float4 Ar[2][2][2];          // [buf][mg][half]
    short8 Bh[2][4], Bl[2][4];   // [buf][nf]

#define PREFETCH(nxt, ksx) do {                                            \
        const int k1_ = kbase + (ksx) * 32 + q * 8;                        \
        Ar[nxt][0][0] = *(const float4*)(xr[0] + k1_);                     \
        Ar[nxt][0][1] = *(const float4*)(xr[0] + k1_ + 4);                 \
        Ar[nxt][1][0] = *(const float4*)(xr[1] + k1_);                     \
        Ar[nxt][1][1] = *(const float4*)(xr[1] + k1_ + 4);                 \
        _Pragma("unroll")                                                  \
        for (int nf_ = 0; nf_ < 4; ++nf_) {                                \
            Bh[nxt][nf_] = *(const short8*)(whi + boff[nf_] + k1_);        \
            Bl[nxt][nf_] = *(const short8*)(wlo + boff[nf_] + k1_);        \
        }                                                                  \
    } while (0)

#define COMPUTE(buf) do {                                                  \
        short8 ahi0_, alo0_, ahi1_, alo1_;                                 \
        cvt8(Ar[buf][0][0], Ar[buf][0][1], ahi0_, alo0_);                  \
        cvt8(Ar[buf][1][0], Ar[buf][1][1], ahi1_, alo1_);                  \
        _Pragma("unroll")                                                  \
        for (int nf_ = 0; nf_ < 4; ++nf_) {                                \
            acc[0][nf_] = __builtin_amdgcn_mfma_f32_16x16x32_bf16(ahi0_, Bl[buf][nf_], acc[0][nf_], 0, 0, 0); \
            acc[0][nf_] = __builtin_amdgcn_mfma_f32_16x16x32_bf16(alo0_, Bh[buf][nf_], acc[0][nf_], 0, 0, 0); \
            acc[0][nf_] = __builtin_amdgcn_mfma_f32_16x16x32_bf16(ahi0_, Bh[buf][nf_], acc[0][nf_], 0, 0, 0); \
            acc[1][nf_] = __builtin_amdgcn_mfma_f32_16x16x32_bf16(ahi1_, Bl[buf][nf_], acc[1][nf_], 0, 0, 0); \
            acc[1][nf_] = __builtin_amdgcn_mfma_f32_16x16x32_bf16(alo1_, Bh[buf][nf_], acc[1][nf_], 0, 0, 0); \
            acc[1][nf_] = __builtin_amdgcn_mfma_f32_16x16x32_bf16(ahi1_, Bh[buf][nf_], acc[1][nf_], 0, 0, 0); \
        }                                                                  \
    } while (0)

#define WALL __builtin_amdgcn_sched_barrier(0)

    // prime the pipeline
    PREFETCH(0, 0);
    WALL;
    #pragma unroll 1
    for (int ks = 0; ks < KSTEPS - 2; ks += 2) {
        PREFETCH(1, ks + 1);
        WALL;
        COMPUTE(0);
        WALL;
        PREFETCH(0, ks + 2);
        WALL;
        COMPUTE(1);
        WALL;
    }
    PREFETCH(1, KSTEPS - 1);
    WALL;
    COMPUTE(0);
    WALL;
    COMPUTE(1);

#undef PREFETCH
#undef COMPUTE
#undef WALL

    // partials -> LDS (C/D layout: col=lane&15 -> expert, row=q*4+r -> token-in-group)
    #pragma unroll
    for (int mg = 0; mg < 2; ++mg)
        #pragma unroll
        for (int nf = 0; nf < 4; ++nf)
            #pragma unroll
            for (int r = 0; r < 4; ++r)
                lds_part[wv][mg * 16 + q * 4 + r][nf * 16 + nl] = acc[mg][nf][r];
    __syncthreads();

    // reduce 8 partials (fixed order), add bias: 2048 values / 512 threads
    #pragma unroll
    for (int i = 0; i < (TB * NEXP) / 512; ++i) {
        const int p  = tid + i * 512;
        const int tk = p >> 6, e = p & 63;
        float s = lds_part[0][tk][e];
        #pragma unroll
        for (int k = 1; k < KSPLIT; ++k) s += lds_part[k][tk][e];
        lds_s[tk][e] = s + bias[e];
    }
    __syncthreads();

    // softmax + parallel-rank top-k: wave wv -> tokens wv*4..+4, lane = expert
    float* __restrict__ out_idx = out + (size_t)ntok * NEXP;
    #pragma unroll
    for (int t = 0; t < 4; ++t) {
        const int tokl = wv * 4 + t;
        const int tok  = tok0 + tokl;
        const float s  = lds_s[tokl][lane];

        float m = s;
        #pragma unroll
        for (int off = 32; off > 0; off >>= 1)
            m = fmaxf(m, __shfl_xor(m, off, 64));
        const float ex = expf(s - m);
        float sum = ex;
        #pragma unroll
        for (int off = 32; off > 0; off >>= 1)
            sum += __shfl_xor(sum, off, 64);
        out[(size_t)tok * NEXP + lane] = ex / sum;

        // rank = #{j : v_j > s || (v_j == s && j < lane)} — parallel top-k.
        int rank = 0;
        #pragma unroll
        for (int i = 0; i < 16; ++i) {
            const float4 v4 = *(const float4*)(&lds_s[tokl][i * 4]);
            rank += (int)((v4.x > s) || (v4.x == s && (i * 4 + 0) < lane));
            rank += (int)((v4.y > s) || (v4.y == s && (i * 4 + 1) < lane));
            rank += (int)((v4.z > s) || (v4.z == s && (i * 4 + 2) < lane));
            rank += (int)((v4.w > s) || (v4.w == s && (i * 4 + 3) < lane));
        }
        if (rank < TOPK_N + 1) top9[tokl][rank] = s;
        if (rank < TOPK_N)
            out_idx[(size_t)tok * TOPK_N + rank] = (float)lane;
    }
    __syncthreads();

    // tie-screen: TB threads, one per token, scan the 8 gaps of top-9
    if (tid < TB) {
        float ming = 1e30f;
        #pragma unroll
        for (int r = 0; r < TOPK_N; ++r)
            ming = fminf(ming, top9[tid][r] - top9[tid][r + 1]);
        if (ming < TAU) {
            const int sl = atomicAdd(&nflag, 1);
            ftok[sl] = tid;
            fninth[sl] = top9[tid][TOPK_N];   // 9th-best fp32 score
        }
    }
    __syncthreads();

    // inline fp64 recheck of flagged tokens (block-local, rare)
    const int nfl = nflag;
    for (int i = 0; i < nfl; ++i) {
        const int tokl = ftok[i];
        const int tok  = tok0 + tokl;
        const float thr = fninth[i] - TAU;
        const unsigned long long cmask = __ballot(lds_s[tokl][lane] >= thr);
        if (wv == 0) dsc[lane] = -1.0e300;
        __syncthreads();
        // wave wv handles candidate ranks wv, wv+8, ...
        {
            int rank = 0;
            unsigned long long mm = cmask;
            while (mm) {
                const int e = __builtin_ctzll(mm);
                mm &= mm - 1;
                if ((rank & 7) == wv) {
                    const float* wr  = wfp + (size_t)e * DIM;
                    const float* xrr = x + (size_t)tok * DIM;
                    double a = 0.0;
                    #pragma unroll 4
                    for (int kk = 0; kk < 16; ++kk) {
                        const int k = kk * 256 + lane * 4;
                        const float4 wv4 = *(const float4*)(wr + k);
                        const float4 xv  = *(const float4*)(xrr + k);
                        a = fma((double)xv.x, (double)wv4.x, a);
                        a = fma((double)xv.y, (double)wv4.y, a);
                        a = fma((double)xv.z, (double)wv4.z, a);
                        a = fma((double)xv.w, (double)wv4.w, a);
                    }
                    #pragma unroll
                    for (int off = 32; off > 0; off >>= 1)
                        a += __shfl_xor(a, off, 64);
                    if (lane == 0) dsc[e] = a + (double)bias[e];
                }
                ++rank;
            }
        }
        __syncthreads();
        if (wv == 0) {
            double cv = dsc[lane];
            for (int r = 0; r < TOPK_N; ++r) {
                double bv = cv;
                int    bi = lane;
                #pragma unroll
                for (int off = 32; off > 0; off >>= 1) {
                    const double ov = __shfl_xor(bv, off, 64);
                    const int    oi = __shfl_xor(bi, off, 64);
                    if (ov > bv || (ov == bv && oi < bi)) { bv = ov; bi = oi; }
                }
                if (lane == r)
                    out_idx[(size_t)tok * TOPK_N + r] = (float)bi;
                if (lane == bi) cv = -1.0e301;
            }
        }
        __syncthreads();
    }
}

extern "C" void kernel_launch(void* const* d_in, const int* in_sizes, int n_in,
                              void* d_out, int out_size, void* d_ws, size_t ws_size,
                              hipStream_t stream) {
    const float* x  = (const float*)d_in[0];
    const float* w  = (const float*)d_in[1];
    const float* bs = (const float*)d_in[2];
    float* out = (float*)d_out;

    unsigned short* whi = (unsigned short*)((char*)d_ws + WS_WHI_OFF);
    unsigned short* wlo = (unsigned short*)((char*)d_ws + WS_WLO_OFF);

    const int ntok = in_sizes[0] / DIM;          // 8192

    hipLaunchKernelGGL(cvt_w_kernel, dim3((NEXP * DIM) / 8 / 256), dim3(256), 0, stream,
                       w, whi, wlo);
    hipLaunchKernelGGL(gemm_kernel, dim3(ntok / TB), dim3(512), 0, stream,
                       x, whi, wlo, bs, w, out, ntok);
}